// Round 15
// baseline (145.286 us; speedup 1.0000x reference)
//
#include <hip/hip_runtime.h>
#include <math.h>

#define N_NODES 100000
#define BSHIFT 8                 // 256-node buckets
#define NBUCK 512                // >= ceil(N/256)=391, pow2
#define CAPSHIFT 12              // 4096 slots per bucket (mean 3061, +19 sigma)
#define CAP (1 << CAPSHIFT)

typedef unsigned short bfu;
typedef unsigned int uint;
typedef __attribute__((ext_vector_type(8))) short short8v;   // 8 bf16 = 4 VGPRs
typedef __attribute__((ext_vector_type(4))) float f32x4;

__device__ __forceinline__ float bf2f(bfu u) {
    union { uint i; float f; } v; v.i = (uint)u << 16; return v.f;
}
__device__ __forceinline__ bfu f2bf(float f) {   // round-to-nearest-even
    union { float f_; uint i; } v; v.f_ = f;
    uint r = (v.i + 0x7FFFu + ((v.i >> 16) & 1u)) >> 16;
    return (bfu)r;
}
__device__ __forceinline__ float asf(uint u) {
    union { uint i; float f; } v; v.i = u; return v.f;
}

// ---------------------------------------------------------------- P1: bin edges by bucket
// Static bucket bases (b*CAP). Packed word cached in registers: dst/src read ONCE.
// 2048-edge chunks -> 586 blocks for occupancy.
__global__ __launch_bounds__(256) void bin_edges(const int* __restrict__ src,
                                                 const int* __restrict__ dst,
                                                 int* __restrict__ gcursor,
                                                 uint* __restrict__ binned, int nE) {
    __shared__ int h[NBUCK];
    __shared__ int base[NBUCK];
    int tid = threadIdx.x;
    int start = blockIdx.x * 2048;
    h[tid] = 0; h[tid + 256] = 0;
    __syncthreads();
    int bkt[8], rnk[8];
    uint pk[8];
    #pragma unroll
    for (int u = 0; u < 8; ++u) {
        int e = start + u * 256 + tid;
        bkt[u] = -1;
        if (e < nE) {
            int d = dst[e];
            int b = d >> BSHIFT;
            bkt[u] = b;
            pk[u] = ((uint)(d & 255) << 17) | (uint)src[e];   // src < 2^17
            rnk[u] = atomicAdd(&h[b], 1);
        }
    }
    __syncthreads();
    #pragma unroll
    for (int i0 = 0; i0 < NBUCK; i0 += 256) {
        int i = i0 + tid;
        base[i] = h[i] ? (i << CAPSHIFT) + atomicAdd(&gcursor[i], h[i]) : 0;
    }
    __syncthreads();
    #pragma unroll
    for (int u = 0; u < 8; ++u) {
        if (bkt[u] >= 0)
            binned[base[bkt[u]] + rnk[u]] = pk[u];
    }
}

// ---------------------------------------------------------------- P2: per-bucket CSR build
// 391 blocks x 256 threads (2x parallelism vs 512-node buckets). Bucket's
// binned words staged once in LDS (16KB); hist/scan/scatter from LDS.
__global__ __launch_bounds__(256) void build_csr(
    const uint* __restrict__ binned, const int* __restrict__ gcursor,
    int* __restrict__ rowptr, int* __restrict__ rowend,
    float* __restrict__ dinv, int* __restrict__ nbr,
    const float4* __restrict__ x, ushort4* __restrict__ z0, int nN) {
    __shared__ uint sbin[CAP];      // 16 KB
    __shared__ int hist[256];
    __shared__ int cursor[256];
    int b = blockIdx.x, t = threadIdx.x;
    int n0 = b << BSHIFT;
    int nNodes = min(256, nN - n0);
    int base = b << CAPSHIFT;
    int cnt = gcursor[b];
    hist[t] = 0;
    __syncthreads();
    for (int i = t; i < cnt; i += 256) {        // single coalesced global read
        uint pk = binned[base + i];
        sbin[i] = pk;
        atomicAdd(&hist[pk >> 17], 1);
    }
    __syncthreads();
    int v = hist[t];
    #pragma unroll
    for (int off = 1; off < 256; off <<= 1) {
        int tv = (t >= off) ? hist[t - off] : 0;
        __syncthreads();
        hist[t] += tv;
        __syncthreads();
    }
    int excl = hist[t] - v;
    float dv = rsqrtf((float)v + 1.0f);           // +1 self loop
    if (t < nNodes) {
        rowptr[n0 + t] = base + excl;
        rowend[n0 + t] = base + excl + v;
        dinv[n0 + t] = dv;
    }
    cursor[t] = excl;
    __syncthreads();
    ((float*)hist)[t] = dv;                        // hist reused as dinv cache
    __syncthreads();
    for (int i = t; i < cnt; i += 256) {           // scatter from LDS
        uint pk = sbin[i];
        int ld = pk >> 17;
        int pos = atomicAdd(&cursor[ld], 1);
        nbr[base + pos] = (int)(pk & 0x1FFFFu);
    }
    // epilogue: z0 rows for this bucket, coalesced
    const float4* xr = x + (size_t)n0 * 16;
    ushort4* zr = z0 + (size_t)n0 * 16;
    int totalF4 = nNodes * 16;
    for (int i = t; i < totalF4; i += 256) {
        float w = ((float*)hist)[i >> 4];
        float4 vv = xr[i];
        ushort4 o;
        o.x = f2bf(w * vv.x); o.y = f2bf(w * vv.y);
        o.z = f2bf(w * vv.z); o.w = f2bf(w * vv.w);
        zr[i] = o;
    }
}

// ---------------------------------------------------------------- gather hop, 8 rows/load
// wave = 1 node; 8 groups of 8 lanes; 128B row per group load (R12 lesson:
// never shrink the random-access quantum below 128B; R13 lesson: keep
// 1 node/wave TLP, don't serialize nodes within a wave).
template<int PW>
__global__ __launch_bounds__(256, 8) void gather_hop8(
    bfu* __restrict__ out, const bfu* __restrict__ z,
    const int* __restrict__ nbr, const int* __restrict__ rowptr,
    const int* __restrict__ rowend, const float* __restrict__ dinv, int nN) {
    int node = blockIdx.x * 4 + (threadIdx.x >> 6);
    if (node >= nN) return;
    int lane = threadIdx.x & 63;
    int g = lane >> 3, k = lane & 7;
    int beg = rowptr[node], end = rowend[node];

    float acc[8];
    #pragma unroll
    for (int i = 0; i < 8; ++i) acc[i] = 0.f;

    auto rowload = [&](int s) -> uint4 {
        return reinterpret_cast<const uint4*>(z + (size_t)s * 64)[k];
    };
    auto accum = [&](uint4 v) {
        acc[0] += asf(v.x << 16); acc[1] += asf(v.x & 0xFFFF0000u);
        acc[2] += asf(v.y << 16); acc[3] += asf(v.y & 0xFFFF0000u);
        acc[4] += asf(v.z << 16); acc[5] += asf(v.z & 0xFFFF0000u);
        acc[6] += asf(v.w << 16); acc[7] += asf(v.w & 0xFFFF0000u);
    };

    if (g == 0)   // self loop
        accum(rowload(node));
    int j = beg + g;
    for (; j + 8 < end; j += 16) {
        int i0 = nbr[j], i1 = nbr[j + 8];
        uint4 v0 = rowload(i0);
        uint4 v1 = rowload(i1);
        accum(v0);
        accum(v1);
    }
    if (j < end)
        accum(rowload(nbr[j]));

    #pragma unroll
    for (int m = 8; m < 64; m <<= 1)
        #pragma unroll
        for (int i = 0; i < 8; ++i)
            acc[i] += __shfl_xor(acc[i], m);

    if (g == 0) {
        float di = dinv[node];
        float w = (PW == 2) ? di * di : di;
        uint4 o;
        o.x = ((uint)f2bf(acc[1] * w) << 16) | f2bf(acc[0] * w);
        o.y = ((uint)f2bf(acc[3] * w) << 16) | f2bf(acc[2] * w);
        o.z = ((uint)f2bf(acc[5] * w) << 16) | f2bf(acc[4] * w);
        o.w = ((uint)f2bf(acc[7] * w) << 16) | f2bf(acc[6] * w);
        reinterpret_cast<uint4*>(out + (size_t)node * 64)[k] = o;
    }
}

// ---------------------------------------------------------------- MFMA MLP + log_softmax
// PERSISTENT: each block stages weights ONCE, then grid-strides over 64-node tiles.
__global__ __launch_bounds__(256) void mlp_mfma(
    float* __restrict__ out, const bfu* __restrict__ zC,
    const float* __restrict__ W1, const float* __restrict__ b1,
    const float* __restrict__ W2, const float* __restrict__ b2,
    int nN, int nTiles) {
    __shared__ short w1t[64 * 72];   // w1t[n][k] bf16
    __shared__ short w2t[48 * 72];   // w2t[n][k] bf16, n 40..47 = 0
    __shared__ short hlds[64 * 72];  // h[node][hid] bf16
    __shared__ float b1s[64];
    __shared__ float b2s[48];

    int tid = threadIdx.x;
    for (int i = tid; i < 64 * 64; i += 256) {
        int k = i >> 6, n = i & 63;
        w1t[n * 72 + k] = (short)f2bf(W1[i]);
    }
    for (int i = tid; i < 48 * 64; i += 256) {
        int k = i / 48, n = i % 48;
        w2t[n * 72 + k] = (short)(n < 40 ? f2bf(W2[k * 40 + n]) : 0);
    }
    if (tid < 64) b1s[tid] = b1[tid];
    if (tid >= 64 && tid < 112) b2s[tid - 64] = (tid - 64 < 40) ? b2[tid - 64] : 0.f;

    int wv = tid >> 6, l = tid & 63;
    int li = l & 15, kg = l >> 4;

    for (int tile = blockIdx.x; tile < nTiles; tile += gridDim.x) {
        int nodebase = tile * 64 + wv * 16;
        int nclamp = min(nodebase + li, nN - 1);

        const short8v* zr = (const short8v*)(zC + (size_t)nclamp * 64);
        short8v a0 = zr[kg];
        short8v a1 = zr[kg + 4];
        __syncthreads();   // weights staged (iter 0); hlds readers done (iter >0)

        f32x4 acc[4];
        #pragma unroll
        for (int nt = 0; nt < 4; ++nt) {
            f32x4 c = {0.f, 0.f, 0.f, 0.f};
            short8v b0 = *(const short8v*)&w1t[(nt * 16 + li) * 72 + kg * 8];
            short8v b1f = *(const short8v*)&w1t[(nt * 16 + li) * 72 + 32 + kg * 8];
            c = __builtin_amdgcn_mfma_f32_16x16x32_bf16(a0, b0, c, 0, 0, 0);
            c = __builtin_amdgcn_mfma_f32_16x16x32_bf16(a1, b1f, c, 0, 0, 0);
            acc[nt] = c;
        }
        #pragma unroll
        for (int nt = 0; nt < 4; ++nt) {
            float bb = b1s[nt * 16 + li];
            #pragma unroll
            for (int r = 0; r < 4; ++r) {
                float v = fmaxf(acc[nt][r] + bb, 0.f);
                hlds[(wv * 16 + kg * 4 + r) * 72 + nt * 16 + li] = (short)f2bf(v);
            }
        }
        __syncthreads();

        const short8v* hp = (const short8v*)&hlds[(wv * 16 + li) * 72];
        short8v ha0 = hp[kg];
        short8v ha1 = hp[kg + 4];
        f32x4 acc2[3];
        #pragma unroll
        for (int nt = 0; nt < 3; ++nt) {
            f32x4 c = {0.f, 0.f, 0.f, 0.f};
            short8v b0 = *(const short8v*)&w2t[(nt * 16 + li) * 72 + kg * 8];
            short8v b1f = *(const short8v*)&w2t[(nt * 16 + li) * 72 + 32 + kg * 8];
            c = __builtin_amdgcn_mfma_f32_16x16x32_bf16(ha0, b0, c, 0, 0, 0);
            c = __builtin_amdgcn_mfma_f32_16x16x32_bf16(ha1, b1f, c, 0, 0, 0);
            acc2[nt] = c;
        }

        float lg[3][4];
        #pragma unroll
        for (int nt = 0; nt < 3; ++nt) {
            float bb = b2s[nt * 16 + li];
            #pragma unroll
            for (int r = 0; r < 4; ++r) lg[nt][r] = acc2[nt][r] + bb;
        }
        bool v2 = (li < 8);   // tile 2 valid cols 32..39
        float mx[4], sm[4];
        #pragma unroll
        for (int r = 0; r < 4; ++r) {
            float m = fmaxf(lg[0][r], lg[1][r]);
            if (v2) m = fmaxf(m, lg[2][r]);
            mx[r] = m;
        }
        #pragma unroll
        for (int off = 1; off < 16; off <<= 1)
            #pragma unroll
            for (int r = 0; r < 4; ++r)
                mx[r] = fmaxf(mx[r], __shfl_xor(mx[r], off));
        #pragma unroll
        for (int r = 0; r < 4; ++r) {
            float s = expf(lg[0][r] - mx[r]) + expf(lg[1][r] - mx[r]);
            if (v2) s += expf(lg[2][r] - mx[r]);
            sm[r] = s;
        }
        #pragma unroll
        for (int off = 1; off < 16; off <<= 1)
            #pragma unroll
            for (int r = 0; r < 4; ++r)
                sm[r] += __shfl_xor(sm[r], off);

        int nb2 = nodebase + kg * 4;
        #pragma unroll
        for (int r = 0; r < 4; ++r) {
            int nd = nb2 + r;
            if (nd < nN) {
                float lse = mx[r] + logf(sm[r]);
                out[(size_t)nd * 40 + li]      = lg[0][r] - lse;
                out[(size_t)nd * 40 + 16 + li] = lg[1][r] - lse;
                if (v2) out[(size_t)nd * 40 + 32 + li] = lg[2][r] - lse;
            }
        }
    }
}

extern "C" void kernel_launch(void* const* d_in, const int* in_sizes, int n_in,
                              void* d_out, int out_size, void* d_ws, size_t ws_size,
                              hipStream_t stream) {
    const float* x   = (const float*)d_in[0];
    const int* eidx  = (const int*)d_in[1];
    const float* W1  = (const float*)d_in[2];
    const float* b1  = (const float*)d_in[3];
    const float* W2  = (const float*)d_in[4];
    const float* b2  = (const float*)d_in[5];
    float* out = (float*)d_out;

    const int nN = N_NODES;
    const int nE = in_sizes[1] / 2;  // edge_index is [2, E]
    const int* src = eidx;
    const int* dst = eidx + nE;
    const int nBk = (nN + 255) >> BSHIFT;   // 391 buckets

    // ---- workspace layout (256B aligned)
    char* ws = (char*)d_ws;
    size_t off = 0;
    auto alloc = [&](size_t bytes) {
        char* p = ws + off;
        off += (bytes + 255) & ~(size_t)255;
        return p;
    };
    float* dinv    = (float*)alloc((size_t)nN * 4);
    int*   gcursor = (int*)  alloc(NBUCK * 4);
    int*   rowptr  = (int*)  alloc((size_t)nN * 4);
    int*   rowend  = (int*)  alloc((size_t)nN * 4);
    uint*  binned  = (uint*) alloc((size_t)NBUCK * CAP * 4);   // 8 MB, gapped
    int*   nbr     = (int*)  alloc((size_t)NBUCK * CAP * 4);   // 8 MB, gapped
    bfu*   z0      = (bfu*)  alloc((size_t)nN * 64 * 2);
    bfu*   zB      = (bfu*)  alloc((size_t)nN * 64 * 2);
    bfu*   zC      = (bfu*)  alloc((size_t)nN * 64 * 2);

    // 1. CSR build: bin (static bucket bases) -> per-bucket build (+dinv, z0)
    hipMemsetAsync(gcursor, 0, NBUCK * 4, stream);
    bin_edges<<<(nE + 2047) / 2048, 256, 0, stream>>>(src, dst, gcursor, binned, nE);
    build_csr<<<nBk, 256, 0, stream>>>(binned, gcursor, rowptr, rowend, dinv, nbr,
                                       (const float4*)x, (ushort4*)z0, nN);

    // 2. zB = bf16(D^-1 (A+I) z0); zC = bf16(D^-1/2 (A+I) zB)
    const int gBlocks = (nN + 3) / 4;
    gather_hop8<2><<<gBlocks, 256, 0, stream>>>(zB, z0, nbr, rowptr, rowend, dinv, nN);
    gather_hop8<1><<<gBlocks, 256, 0, stream>>>(zC, zB, nbr, rowptr, rowend, dinv, nN);

    // 3. persistent MFMA MLP + log_softmax
    const int nTiles = (nN + 63) / 64;
    mlp_mfma<<<392, 256, 0, stream>>>(out, zC, W1, b1, W2, b2, nN, nTiles);
}

// Round 16
// 142.881 us; speedup vs baseline: 1.0168x; 1.0168x over previous
//
#include <hip/hip_runtime.h>
#include <math.h>

#define N_NODES 100000
#define BSHIFT 9                 // 512-node buckets
#define NBUCK 256                // >= ceil(N/512)=196, pow2
#define CAPSHIFT 13              // 8192 slots per bucket (mean 6122, +26 sigma)
#define CAP (1 << CAPSHIFT)

typedef unsigned short bfu;
typedef unsigned int uint;
typedef __attribute__((ext_vector_type(8))) short short8v;   // 8 bf16 = 4 VGPRs
typedef __attribute__((ext_vector_type(4))) float f32x4;

__device__ __forceinline__ float bf2f(bfu u) {
    union { uint i; float f; } v; v.i = (uint)u << 16; return v.f;
}
__device__ __forceinline__ bfu f2bf(float f) {   // round-to-nearest-even
    union { float f_; uint i; } v; v.f_ = f;
    uint r = (v.i + 0x7FFFu + ((v.i >> 16) & 1u)) >> 16;
    return (bfu)r;
}
__device__ __forceinline__ float asf(uint u) {
    union { uint i; float f; } v; v.i = u; return v.f;
}

// ---------------------------------------------------------------- P1: bin edges by bucket
// Static bucket bases (b*CAP). Packed word cached in registers: dst/src read ONCE.
__global__ __launch_bounds__(256) void bin_edges(const int* __restrict__ src,
                                                 const int* __restrict__ dst,
                                                 int* __restrict__ gcursor,
                                                 uint* __restrict__ binned, int nE) {
    __shared__ int h[NBUCK];
    __shared__ int base[NBUCK];
    int tid = threadIdx.x;
    int start = blockIdx.x * 4096;
    h[tid] = 0;
    __syncthreads();
    int bkt[16], rnk[16];
    uint pk[16];
    #pragma unroll
    for (int u = 0; u < 16; ++u) {
        int e = start + u * 256 + tid;
        bkt[u] = -1;
        if (e < nE) {
            int d = dst[e];
            int b = d >> BSHIFT;
            bkt[u] = b;
            pk[u] = ((uint)(d & 511) << 17) | (uint)src[e];   // src < 2^17
            rnk[u] = atomicAdd(&h[b], 1);
        }
    }
    __syncthreads();
    base[tid] = h[tid] ? (tid << CAPSHIFT) + atomicAdd(&gcursor[tid], h[tid]) : 0;
    __syncthreads();
    #pragma unroll
    for (int u = 0; u < 16; ++u) {
        if (bkt[u] >= 0)
            binned[base[bkt[u]] + rnk[u]] = pk[u];
    }
}

// ---------------------------------------------------------------- P2: per-bucket CSR build
// Bucket's binned words staged once in LDS (32KB); hist/scan/scatter from LDS.
// Outputs: rowptr/rowend, dinv, nbr (gapped), z0 = bf16(dinv*x).
__global__ __launch_bounds__(512) void build_csr(
    const uint* __restrict__ binned, const int* __restrict__ gcursor,
    int* __restrict__ rowptr, int* __restrict__ rowend,
    float* __restrict__ dinv, int* __restrict__ nbr,
    const float4* __restrict__ x, ushort4* __restrict__ z0, int nN) {
    __shared__ uint sbin[CAP];      // 32 KB
    __shared__ int hist[512];
    __shared__ int cursor[512];
    int b = blockIdx.x, t = threadIdx.x;
    int n0 = b << BSHIFT;
    int nNodes = min(512, nN - n0);
    int base = b << CAPSHIFT;
    int cnt = gcursor[b];
    hist[t] = 0;
    __syncthreads();
    for (int i = t; i < cnt; i += 512) {        // single coalesced global read
        uint pk = binned[base + i];
        sbin[i] = pk;
        atomicAdd(&hist[pk >> 17], 1);
    }
    __syncthreads();
    int v = hist[t];
    #pragma unroll
    for (int off = 1; off < 512; off <<= 1) {
        int tv = (t >= off) ? hist[t - off] : 0;
        __syncthreads();
        hist[t] += tv;
        __syncthreads();
    }
    int excl = hist[t] - v;
    float dv = rsqrtf((float)v + 1.0f);           // +1 self loop
    if (t < nNodes) {
        rowptr[n0 + t] = base + excl;
        rowend[n0 + t] = base + excl + v;
        dinv[n0 + t] = dv;
    }
    cursor[t] = excl;
    __syncthreads();
    ((float*)hist)[t] = dv;                        // hist reused as dinv cache
    __syncthreads();
    for (int i = t; i < cnt; i += 512) {           // scatter from LDS
        uint pk = sbin[i];
        int ld = pk >> 17;
        int pos = atomicAdd(&cursor[ld], 1);
        nbr[base + pos] = (int)(pk & 0x1FFFFu);
    }
    // epilogue: z0 rows for this bucket, coalesced
    const float4* xr = x + (size_t)n0 * 16;
    ushort4* zr = z0 + (size_t)n0 * 16;
    int totalF4 = nNodes * 16;
    for (int i = t; i < totalF4; i += 512) {
        float w = ((float*)hist)[i >> 4];
        float4 vv = xr[i];
        ushort4 o;
        o.x = f2bf(w * vv.x); o.y = f2bf(w * vv.y);
        o.z = f2bf(w * vv.z); o.w = f2bf(w * vv.w);
        zr[i] = o;
    }
}

// ---------------------------------------------------------------- gather hop, 8 rows/load
// wave = 1 node; 8 groups of 8 lanes; 128B row per group load (R12 lesson:
// never shrink the random-access quantum below 128B; R13 lesson: keep
// 1 node/wave TLP, don't serialize nodes within a wave).
template<int PW>
__global__ __launch_bounds__(256, 8) void gather_hop8(
    bfu* __restrict__ out, const bfu* __restrict__ z,
    const int* __restrict__ nbr, const int* __restrict__ rowptr,
    const int* __restrict__ rowend, const float* __restrict__ dinv, int nN) {
    int node = blockIdx.x * 4 + (threadIdx.x >> 6);
    if (node >= nN) return;
    int lane = threadIdx.x & 63;
    int g = lane >> 3, k = lane & 7;
    int beg = rowptr[node], end = rowend[node];

    float acc[8];
    #pragma unroll
    for (int i = 0; i < 8; ++i) acc[i] = 0.f;

    auto rowload = [&](int s) -> uint4 {
        return reinterpret_cast<const uint4*>(z + (size_t)s * 64)[k];
    };
    auto accum = [&](uint4 v) {
        acc[0] += asf(v.x << 16); acc[1] += asf(v.x & 0xFFFF0000u);
        acc[2] += asf(v.y << 16); acc[3] += asf(v.y & 0xFFFF0000u);
        acc[4] += asf(v.z << 16); acc[5] += asf(v.z & 0xFFFF0000u);
        acc[6] += asf(v.w << 16); acc[7] += asf(v.w & 0xFFFF0000u);
    };

    if (g == 0)   // self loop
        accum(rowload(node));
    int j = beg + g;
    for (; j + 8 < end; j += 16) {
        int i0 = nbr[j], i1 = nbr[j + 8];
        uint4 v0 = rowload(i0);
        uint4 v1 = rowload(i1);
        accum(v0);
        accum(v1);
    }
    if (j < end)
        accum(rowload(nbr[j]));

    #pragma unroll
    for (int m = 8; m < 64; m <<= 1)
        #pragma unroll
        for (int i = 0; i < 8; ++i)
            acc[i] += __shfl_xor(acc[i], m);

    if (g == 0) {
        float di = dinv[node];
        float w = (PW == 2) ? di * di : di;
        uint4 o;
        o.x = ((uint)f2bf(acc[1] * w) << 16) | f2bf(acc[0] * w);
        o.y = ((uint)f2bf(acc[3] * w) << 16) | f2bf(acc[2] * w);
        o.z = ((uint)f2bf(acc[5] * w) << 16) | f2bf(acc[4] * w);
        o.w = ((uint)f2bf(acc[7] * w) << 16) | f2bf(acc[6] * w);
        reinterpret_cast<uint4*>(out + (size_t)node * 64)[k] = o;
    }
}

// ---------------------------------------------------------------- MFMA MLP + log_softmax
// PERSISTENT: each block stages weights ONCE, then grid-strides over 64-node tiles.
__global__ __launch_bounds__(256) void mlp_mfma(
    float* __restrict__ out, const bfu* __restrict__ zC,
    const float* __restrict__ W1, const float* __restrict__ b1,
    const float* __restrict__ W2, const float* __restrict__ b2,
    int nN, int nTiles) {
    __shared__ short w1t[64 * 72];   // w1t[n][k] bf16
    __shared__ short w2t[48 * 72];   // w2t[n][k] bf16, n 40..47 = 0
    __shared__ short hlds[64 * 72];  // h[node][hid] bf16
    __shared__ float b1s[64];
    __shared__ float b2s[48];

    int tid = threadIdx.x;
    for (int i = tid; i < 64 * 64; i += 256) {
        int k = i >> 6, n = i & 63;
        w1t[n * 72 + k] = (short)f2bf(W1[i]);
    }
    for (int i = tid; i < 48 * 64; i += 256) {
        int k = i / 48, n = i % 48;
        w2t[n * 72 + k] = (short)(n < 40 ? f2bf(W2[k * 40 + n]) : 0);
    }
    if (tid < 64) b1s[tid] = b1[tid];
    if (tid >= 64 && tid < 112) b2s[tid - 64] = (tid - 64 < 40) ? b2[tid - 64] : 0.f;

    int wv = tid >> 6, l = tid & 63;
    int li = l & 15, kg = l >> 4;

    for (int tile = blockIdx.x; tile < nTiles; tile += gridDim.x) {
        int nodebase = tile * 64 + wv * 16;
        int nclamp = min(nodebase + li, nN - 1);

        const short8v* zr = (const short8v*)(zC + (size_t)nclamp * 64);
        short8v a0 = zr[kg];
        short8v a1 = zr[kg + 4];
        __syncthreads();   // weights staged (iter 0); hlds readers done (iter >0)

        f32x4 acc[4];
        #pragma unroll
        for (int nt = 0; nt < 4; ++nt) {
            f32x4 c = {0.f, 0.f, 0.f, 0.f};
            short8v b0 = *(const short8v*)&w1t[(nt * 16 + li) * 72 + kg * 8];
            short8v b1f = *(const short8v*)&w1t[(nt * 16 + li) * 72 + 32 + kg * 8];
            c = __builtin_amdgcn_mfma_f32_16x16x32_bf16(a0, b0, c, 0, 0, 0);
            c = __builtin_amdgcn_mfma_f32_16x16x32_bf16(a1, b1f, c, 0, 0, 0);
            acc[nt] = c;
        }
        #pragma unroll
        for (int nt = 0; nt < 4; ++nt) {
            float bb = b1s[nt * 16 + li];
            #pragma unroll
            for (int r = 0; r < 4; ++r) {
                float v = fmaxf(acc[nt][r] + bb, 0.f);
                hlds[(wv * 16 + kg * 4 + r) * 72 + nt * 16 + li] = (short)f2bf(v);
            }
        }
        __syncthreads();

        const short8v* hp = (const short8v*)&hlds[(wv * 16 + li) * 72];
        short8v ha0 = hp[kg];
        short8v ha1 = hp[kg + 4];
        f32x4 acc2[3];
        #pragma unroll
        for (int nt = 0; nt < 3; ++nt) {
            f32x4 c = {0.f, 0.f, 0.f, 0.f};
            short8v b0 = *(const short8v*)&w2t[(nt * 16 + li) * 72 + kg * 8];
            short8v b1f = *(const short8v*)&w2t[(nt * 16 + li) * 72 + 32 + kg * 8];
            c = __builtin_amdgcn_mfma_f32_16x16x32_bf16(ha0, b0, c, 0, 0, 0);
            c = __builtin_amdgcn_mfma_f32_16x16x32_bf16(ha1, b1f, c, 0, 0, 0);
            acc2[nt] = c;
        }

        float lg[3][4];
        #pragma unroll
        for (int nt = 0; nt < 3; ++nt) {
            float bb = b2s[nt * 16 + li];
            #pragma unroll
            for (int r = 0; r < 4; ++r) lg[nt][r] = acc2[nt][r] + bb;
        }
        bool v2 = (li < 8);   // tile 2 valid cols 32..39
        float mx[4], sm[4];
        #pragma unroll
        for (int r = 0; r < 4; ++r) {
            float m = fmaxf(lg[0][r], lg[1][r]);
            if (v2) m = fmaxf(m, lg[2][r]);
            mx[r] = m;
        }
        #pragma unroll
        for (int off = 1; off < 16; off <<= 1)
            #pragma unroll
            for (int r = 0; r < 4; ++r)
                mx[r] = fmaxf(mx[r], __shfl_xor(mx[r], off));
        #pragma unroll
        for (int r = 0; r < 4; ++r) {
            float s = expf(lg[0][r] - mx[r]) + expf(lg[1][r] - mx[r]);
            if (v2) s += expf(lg[2][r] - mx[r]);
            sm[r] = s;
        }
        #pragma unroll
        for (int off = 1; off < 16; off <<= 1)
            #pragma unroll
            for (int r = 0; r < 4; ++r)
                sm[r] += __shfl_xor(sm[r], off);

        int nb2 = nodebase + kg * 4;
        #pragma unroll
        for (int r = 0; r < 4; ++r) {
            int nd = nb2 + r;
            if (nd < nN) {
                float lse = mx[r] + logf(sm[r]);
                out[(size_t)nd * 40 + li]      = lg[0][r] - lse;
                out[(size_t)nd * 40 + 16 + li] = lg[1][r] - lse;
                if (v2) out[(size_t)nd * 40 + 32 + li] = lg[2][r] - lse;
            }
        }
    }
}

extern "C" void kernel_launch(void* const* d_in, const int* in_sizes, int n_in,
                              void* d_out, int out_size, void* d_ws, size_t ws_size,
                              hipStream_t stream) {
    const float* x   = (const float*)d_in[0];
    const int* eidx  = (const int*)d_in[1];
    const float* W1  = (const float*)d_in[2];
    const float* b1  = (const float*)d_in[3];
    const float* W2  = (const float*)d_in[4];
    const float* b2  = (const float*)d_in[5];
    float* out = (float*)d_out;

    const int nN = N_NODES;
    const int nE = in_sizes[1] / 2;  // edge_index is [2, E]
    const int* src = eidx;
    const int* dst = eidx + nE;
    const int nBk = (nN + 511) >> BSHIFT;   // 196 buckets

    // ---- workspace layout (256B aligned)
    char* ws = (char*)d_ws;
    size_t off = 0;
    auto alloc = [&](size_t bytes) {
        char* p = ws + off;
        off += (bytes + 255) & ~(size_t)255;
        return p;
    };
    float* dinv    = (float*)alloc((size_t)nN * 4);
    int*   gcursor = (int*)  alloc(NBUCK * 4);
    int*   rowptr  = (int*)  alloc((size_t)nN * 4);
    int*   rowend  = (int*)  alloc((size_t)nN * 4);
    uint*  binned  = (uint*) alloc((size_t)NBUCK * CAP * 4);   // 8 MB, gapped
    int*   nbr     = (int*)  alloc((size_t)NBUCK * CAP * 4);   // 8 MB, gapped
    bfu*   z0      = (bfu*)  alloc((size_t)nN * 64 * 2);
    bfu*   zB      = (bfu*)  alloc((size_t)nN * 64 * 2);
    bfu*   zC      = (bfu*)  alloc((size_t)nN * 64 * 2);

    // 1. CSR build: bin (static bucket bases) -> per-bucket build (+dinv, z0)
    hipMemsetAsync(gcursor, 0, NBUCK * 4, stream);
    bin_edges<<<(nE + 4095) / 4096, 256, 0, stream>>>(src, dst, gcursor, binned, nE);
    build_csr<<<nBk, 512, 0, stream>>>(binned, gcursor, rowptr, rowend, dinv, nbr,
                                       (const float4*)x, (ushort4*)z0, nN);

    // 2. zB = bf16(D^-1 (A+I) z0); zC = bf16(D^-1/2 (A+I) zB)
    const int gBlocks = (nN + 3) / 4;
    gather_hop8<2><<<gBlocks, 256, 0, stream>>>(zB, z0, nbr, rowptr, rowend, dinv, nN);
    gather_hop8<1><<<gBlocks, 256, 0, stream>>>(zC, zB, nbr, rowptr, rowend, dinv, nN);

    // 3. persistent MFMA MLP + log_softmax
    const int nTiles = (nN + 63) / 64;
    mlp_mfma<<<392, 256, 0, stream>>>(out, zC, W1, b1, W2, b2, nN, nTiles);
}